// Round 9
// baseline (1006.295 us; speedup 1.0000x reference)
//
#include <hip/hip_runtime.h>
#include <cstdint>
#include <cstddef>

// Problem constants (R,1,C) x, t, (K,C) A, (T,) bar_alpha
#define R_DIM 4096
#define K_DIM 16384
#define C_DIM 512
#define SPLITS 4                 // split over the 16384 k-dimension
#define BM 64                    // rows per workgroup
#define BK 128                   // k-tile
#define KRANGE (K_DIM / SPLITS)  // 4096
#define NTILES (KRANGE / BK)     // 32
#define GTILES (K_DIM / BK)      // 128 global tiles

typedef unsigned short us8 __attribute__((ext_vector_type(8)));
typedef float f32x4 __attribute__((ext_vector_type(4)));
typedef __bf16 bfv8 __attribute__((ext_vector_type(8)));

#define MFMA16(a, b, c) __builtin_amdgcn_mfma_f32_16x16x32_bf16((a), (b), (c), 0, 0, 0)
#define BC(v) __builtin_bit_cast(bfv8, (v))

__device__ __forceinline__ unsigned short f2bf(float v) {
    union { float f; unsigned u; } x; x.f = v;
    unsigned r = x.u + 0x7fffu + ((x.u >> 16) & 1u);  // RNE
    return (unsigned short)(r >> 16);
}
__device__ __forceinline__ float bf2f(unsigned short b) {
    union { unsigned u; float f; } x; x.u = ((unsigned)b) << 16;
    return x.f;
}

// async global->LDS, 16B per lane.
__device__ __forceinline__ void gload16(const char* g, char* l) {
    __builtin_amdgcn_global_load_lds(
        (const __attribute__((address_space(1))) void*)g,
        (__attribute__((address_space(3))) void*)l, 16, 0, 0);
}

// ---------------- workspace layout (bytes) ----------------
#define OFF_IMGA ((size_t)0)          // [GTILES][8][32768]  32 MB   [128k][64c] images
#define OFF_IMGC ((size_t)33554432)   // [GTILES][8][32768]  32 MB   [64c][128k] images
#define OFF_XH   ((size_t)67108864)   // [R][C] bf16 hi    4 MB
#define OFF_XL   ((size_t)71303168)   // [R][C] bf16 lo    4 MB
#define OFF_ASQ  ((size_t)75497472)   // [K] f32          64 KB
#define OFF_ROWP ((size_t)75563008)   // [R] float4       64 KB  {sa, 0.5*sa*sa, inv*log2e, inv}
#define OFF_PO   ((size_t)75628544)   // [R][SPLITS][C] f32  32 MB
#define OFF_PM   ((size_t)109182976)  // [R][SPLITS] f32  64 KB
#define OFF_PL   ((size_t)109248512)  // [R][SPLITS] f32  64 KB
#define WS_NEED  ((size_t)109314048)

// ---------------- LDS layout (bytes) ----------------
#define SM_BUF0 0        // staging buffer 0: 32 KB (hi 16K, lo 16K)
#define SM_BUF1 32768    // staging buffer 1: 32 KB (also S-merge scratch at Phase B)
#define SM_U    65536    // u hi [64m][128k] bf16 swizzled  16 KB
#define SM_U2   81920    // u lo                            16 KB
#define SM_MX   98304    // float[2][64] tile-max exchange 512 B
#define SM_SM   98816    // float[2][64] tile-sum exchange 512 B
#define SM_AL   99328    // float[64] al broadcast         256 B
#define SM_TOT  99584

// ======================= prep kernels (identical to round 8) =======================

__global__ void k_rows(const int* __restrict__ t, const float* __restrict__ bar_alpha,
                       float4* __restrict__ rowp) {
    int r = blockIdx.x * 256 + threadIdx.x;
    if (r >= R_DIM) return;
    float ba = bar_alpha[t[r]];
    float sa = sqrtf(ba);
    float inv = 1.0f / (1.0f - ba);
    rowp[r] = make_float4(sa, 0.5f * sa * sa, inv * 1.4426950408889634f, inv);
}

__global__ void k_splitx(const float* __restrict__ x, us8* __restrict__ xh, us8* __restrict__ xl) {
    int i = blockIdx.x * 256 + threadIdx.x;   // group of 8 elements
    if (i >= R_DIM * C_DIM / 8) return;
    const float4* x4 = (const float4*)x + (size_t)i * 2;
    float v[8];
    float4 a = x4[0], b = x4[1];
    v[0]=a.x; v[1]=a.y; v[2]=a.z; v[3]=a.w; v[4]=b.x; v[5]=b.y; v[6]=b.z; v[7]=b.w;
    us8 h, l;
#pragma unroll
    for (int j = 0; j < 8; ++j) {
        unsigned short hb = f2bf(v[j]);
        h[j] = hb;
        l[j] = f2bf(v[j] - bf2f(hb));
    }
    xh[i] = h; xl[i] = l;
}

// Phase-A chunk images: block = (gt, j). pos = kl*128 + ((cb*16) ^ ((kl&7)<<4))
__global__ __launch_bounds__(256) void k_imgA(const float* __restrict__ A, char* __restrict__ img) {
    int gt = blockIdx.x >> 3, j = blockIdx.x & 7;
    char* base = img + (size_t)blockIdx.x * 32768;
    int t = threadIdx.x;
#pragma unroll
    for (int it = 0; it < 4; ++it) {
        int p = t + it * 256;
        int kl = p >> 3, cb = p & 7;
        const float* src = A + (size_t)(gt * 128 + kl) * C_DIM + j * 64 + cb * 8;
        us8 h, l;
#pragma unroll
        for (int q = 0; q < 8; ++q) {
            float v = src[q];
            unsigned short hb = f2bf(v);
            h[q] = hb; l[q] = f2bf(v - bf2f(hb));
        }
        int pos = kl * 128 + ((cb * 16) ^ ((kl & 7) << 4));
        *(us8*)(base + pos) = h;
        *(us8*)(base + 16384 + pos) = l;
    }
}

// Phase-C chunk images (transposed): pos = cl*256 + ((kb*16) ^ ((cl&7)<<4))
__global__ __launch_bounds__(256) void k_imgC(const float* __restrict__ A, char* __restrict__ img) {
    int gt = blockIdx.x >> 3, j = blockIdx.x & 7;
    char* base = img + (size_t)blockIdx.x * 32768;
    int t = threadIdx.x;
#pragma unroll
    for (int it = 0; it < 4; ++it) {
        int p = t + it * 256;
        int cl = p & 63, kb = p >> 6;
        us8 h, l;
#pragma unroll
        for (int q = 0; q < 8; ++q) {
            float v = A[(size_t)(gt * 128 + kb * 8 + q) * C_DIM + j * 64 + cl];
            unsigned short hb = f2bf(v);
            h[q] = hb; l[q] = f2bf(v - bf2f(hb));
        }
        int pos = cl * 256 + ((kb * 16) ^ ((cl & 7) << 4));
        *(us8*)(base + pos) = h;
        *(us8*)(base + 16384 + pos) = l;
    }
}

__global__ void k_asq(const float* __restrict__ A, float* __restrict__ Asq) {
    int wid = threadIdx.x >> 6, lane = threadIdx.x & 63;
    int k = blockIdx.x * 4 + wid;
    const float4* a4 = (const float4*)(A + (size_t)k * C_DIM);
    float s = 0.f;
#pragma unroll
    for (int j = 0; j < 2; ++j) {
        float4 v = a4[lane * 2 + j];
        s += v.x * v.x + v.y * v.y + v.z * v.z + v.w * v.w;
    }
#pragma unroll
    for (int off = 32; off; off >>= 1) s += __shfl_xor(s, off);
    if (lane == 0) Asq[k] = s;
}

// ======================= fused flash-style kernel =======================
// Round-8 topology FROZEN (split=b&3, rb=b>>2; same images; same x issue bytes).
// ONE change: 1024 threads = 16 waves (4/SIMD) for latency hiding.
//  wr = wid>>2 (row-group, 16 rows), wc = (wid>>1)&1, wt = wid&1.
//  Phase A: wave computes S-partial over its 32-col half (cs = wt) -> one
//  32 KB LDS merge per tile into the dead A7 buffer (BUF1, deterministic).
//  Softmax: wt=0 team (8 waves), identical r8 code; al broadcast via SM_AL.
//  Phase C: c split 4 ways (wc,wt), full k per wave, of[8] (32 VGPR).
__global__ __launch_bounds__(1024, 4) void k_fused(
    const char* __restrict__ imgA, const char* __restrict__ imgC,
    const unsigned short* __restrict__ xh, const unsigned short* __restrict__ xl,
    const float* __restrict__ Asq, const float4* __restrict__ rowp,
    float* __restrict__ pO, float* __restrict__ pM, float* __restrict__ pL)
{
    extern __shared__ char smem[];
    const int tid = threadIdx.x;
    const int lane = tid & 63, wid = tid >> 6;
    const int wr = wid >> 2, wc = (wid >> 1) & 1, wt = wid & 1;
    const int l15 = lane & 15, l4 = lane >> 4;
    const int rb = (blockIdx.x >> 2) * BM;
    const int split = blockIdx.x & (SPLITS - 1);

    float sa[4], hb[4], ce[4];
#pragma unroll
    for (int q = 0; q < 4; ++q) {
        float4 p = rowp[rb + wr * 16 + l4 * 4 + q];
        sa[q] = p.x; hb[q] = p.y; ce[q] = p.z;
    }
    float Mr[4], Lr[4];
#pragma unroll
    for (int q = 0; q < 4; ++q) { Mr[q] = -1e30f; Lr[q] = 0.f; }
    f32x4 of[8];   // [c-chunk j]; this wave's 16-col slice c = wc*32 + wt*16
#pragma unroll
    for (int a = 0; a < 8; ++a) of[a] = (f32x4){0.f, 0.f, 0.f, 0.f};

    const int xrow = (rb + wr * 16 + l15) * C_DIM;
    const int stg = tid * 16;   // 0..16K-16

    // prologue: stage A(tile 0, chunk 0) 32 KB into BUF0
    {
        const char* s = imgA + (size_t)(split * NTILES) * 8 * 32768;
        char* d = smem + SM_BUF0;
        gload16(s + stg, d + stg);
        gload16(s + stg + 16384, d + stg + 16384);
    }
    __syncthreads();
    int cur = 0;

    for (int kt = 0; kt < NTILES; ++kt) {
        const int gt = split * NTILES + kt;
        const int kbase = gt * BK;
        f32x4 sf[4];
#pragma unroll
        for (int f = 0; f < 4; ++f) sf[f] = (f32x4){0.f, 0.f, 0.f, 0.f};

        // ---------- Phase A: S[64m][128k], 8 chunks of 64 c; wave does 32-c half ----------
        us8 xbh[2], xbl[2];
        {
            int off = xrow + wt * 32 + l4 * 8;
            xbh[0] = *(const us8*)(xh + off);
            xbl[0] = *(const us8*)(xl + off);
        }
#pragma unroll
        for (int j = 0; j < 8; ++j) {
            {   // stage next chunk (A j+1 hi+lo, or C 0 hi-only when j==7)
                char* d = smem + (cur ? SM_BUF0 : SM_BUF1);
                if (j < 7) {
                    const char* s = imgA + ((size_t)gt * 8 + j + 1) * 32768;
                    gload16(s + stg, d + stg);
                    gload16(s + stg + 16384, d + stg + 16384);
                } else {
                    const char* s = imgC + ((size_t)gt * 8 + 0) * 32768;
                    gload16(s + stg, d + stg);
                }
            }
            if (j < 7) {   // prefetch next chunk's x frag
                int off = xrow + (j + 1) * 64 + wt * 32 + l4 * 8;
                xbh[(j + 1) & 1] = *(const us8*)(xh + off);
                xbl[(j + 1) & 1] = *(const us8*)(xl + off);
            }
            const char* B = smem + (cur ? SM_BUF1 : SM_BUF0);
#pragma unroll
            for (int f = 0; f < 4; ++f) {
                int row = wc * 64 + f * 16 + l15;              // k-index in tile
                int byte = row * 128 + ((wt * 64 + l4 * 16) ^ ((row & 7) << 4));
                bfv8 qh = *(const bfv8*)(B + byte);
                bfv8 ql = *(const bfv8*)(B + 16384 + byte);
                sf[f] = MFMA16(BC(xbh[j & 1]), qh, sf[f]);
                sf[f] = MFMA16(BC(xbh[j & 1]), ql, sf[f]);
                sf[f] = MFMA16(BC(xbl[j & 1]), qh, sf[f]);
            }
            __syncthreads();
            cur ^= 1;
        }

        // ---------- S-merge: BUF1 holds dead A-chunk-7 data (deterministic parity) ----------
        // layout [f][wave(wr*2+wc)][lane] f32x4: lane stride 16 B -> conflict-free
        float* mrg = (float*)(smem + SM_BUF1);
        const int mb = ((wr * 2 + wc) * 64 + lane) * 4;
        if (wt == 1) {
#pragma unroll
            for (int f = 0; f < 4; ++f)
                *(f32x4*)(mrg + f * 2048 + mb) = sf[f];
        }
        __syncthreads();

        // ---------- Phase B: online softmax (wt=0 team; r8 code) ----------
        float Mn[4], al[4];
        float* smax = (float*)(smem + SM_MX);
        float* ssum = (float*)(smem + SM_SM);
        float* albc = (float*)(smem + SM_AL);
        float asq[4];
        if (wt == 0) {
#pragma unroll
            for (int f = 0; f < 4; ++f) {
                sf[f] += *(const f32x4*)(mrg + f * 2048 + mb);
                asq[f] = Asq[kbase + wc * 64 + f * 16 + l15];
            }
            float tmax[4];
#pragma unroll
            for (int q = 0; q < 4; ++q) {
                float g0 = sa[q] * sf[0][q] - hb[q] * asq[0];
                float g1 = sa[q] * sf[1][q] - hb[q] * asq[1];
                float g2 = sa[q] * sf[2][q] - hb[q] * asq[2];
                float g3 = sa[q] * sf[3][q] - hb[q] * asq[3];
                tmax[q] = fmaxf(fmaxf(g0, g1), fmaxf(g2, g3));
            }
#pragma unroll
            for (int off = 1; off < 16; off <<= 1)
#pragma unroll
                for (int q = 0; q < 4; ++q) tmax[q] = fmaxf(tmax[q], __shfl_xor(tmax[q], off));
            if (l15 == 0) {
#pragma unroll
                for (int q = 0; q < 4; ++q) smax[wc * 64 + wr * 16 + l4 * 4 + q] = tmax[q];
            }
        }
        __syncthreads();
        if (wt == 0) {
            float tsum[4] = {0.f, 0.f, 0.f, 0.f};
#pragma unroll
            for (int q = 0; q < 4; ++q) {
                float own = smax[wc * 64 + wr * 16 + l4 * 4 + q];
                float other = smax[(wc ^ 1) * 64 + wr * 16 + l4 * 4 + q];
                Mn[q] = fmaxf(Mr[q], fmaxf(own, other));
                al[q] = exp2f((Mr[q] - Mn[q]) * ce[q]);
            }
#pragma unroll
            for (int f = 0; f < 4; ++f)
#pragma unroll
                for (int q = 0; q < 4; ++q) {
                    float g = sa[q] * sf[f][q] - hb[q] * asq[f];
                    float u = exp2f((g - Mn[q]) * ce[q]);
                    tsum[q] += u;
                    int m_loc = wr * 16 + l4 * 4 + q;
                    int k_loc = wc * 64 + f * 16 + l15;
                    int byte = (m_loc * 256 + k_loc * 2) ^ ((m_loc & 7) << 4);
                    unsigned short uh = f2bf(u);
                    *(unsigned short*)(smem + SM_U + byte) = uh;
                    *(unsigned short*)(smem + SM_U2 + byte) = f2bf(u - bf2f(uh));
                }
#pragma unroll
            for (int off = 1; off < 16; off <<= 1)
#pragma unroll
                for (int q = 0; q < 4; ++q) tsum[q] += __shfl_xor(tsum[q], off);
            if (l15 == 0) {
#pragma unroll
                for (int q = 0; q < 4; ++q) {
                    ssum[wc * 64 + wr * 16 + l4 * 4 + q] = tsum[q];
                    if (wc == 0) albc[wr * 16 + l4 * 4 + q] = 0.f;  // placeholder ordering
                }
            }
            // write al broadcast (both wc write identical values; race benign)
            if (l15 == 0) {
#pragma unroll
                for (int q = 0; q < 4; ++q) albc[wr * 16 + l4 * 4 + q] = al[q];
            }
            // stash tsum in Lr-side temp via registers: fold into Lr after barrier
#pragma unroll
            for (int q = 0; q < 4; ++q) Mr[q] = Mn[q];   // Mn needed after barrier only via Mr
#pragma unroll
            for (int q = 0; q < 4; ++q) sf[0][q] = tsum[q];  // reuse dead sf as tsum carrier
        }
        __syncthreads();

        // ---------- all waves: rescale of, load u frags ----------
        float alr[4];
#pragma unroll
        for (int q = 0; q < 4; ++q) alr[q] = albc[wr * 16 + l4 * 4 + q];
#pragma unroll
        for (int a = 0; a < 8; ++a)
#pragma unroll
            for (int q = 0; q < 4; ++q) of[a][q] *= alr[q];
        us8 uhf[4], ulf[4];
#pragma unroll
        for (int ks = 0; ks < 4; ++ks) {
            int m_loc = wr * 16 + l15;
            int byte = (m_loc * 256 + ks * 64 + l4 * 16) ^ ((m_loc & 7) << 4);
            uhf[ks] = *(const us8*)(smem + SM_U + byte);
            ulf[ks] = *(const us8*)(smem + SM_U2 + byte);
        }
        if (wt == 0) {
#pragma unroll
            for (int q = 0; q < 4; ++q) {
                float others = ssum[(wc ^ 1) * 64 + wr * 16 + l4 * 4 + q];
                Lr[q] = Lr[q] * alr[q] + sf[0][q] + others;
            }
        }

        // ---------- Phase C: O[64m][512c] += (uh+ul)*Ah, 8 chunks; wave owns 16 c ----------
#pragma unroll
        for (int j = 0; j < 8; ++j) {
            if (j < 7) {
                const char* s = imgC + ((size_t)gt * 8 + j + 1) * 32768;
                char* d = smem + (cur ? SM_BUF0 : SM_BUF1);
                gload16(s + stg, d + stg);
            } else if (kt < NTILES - 1) {
                const char* s = imgA + ((size_t)(gt + 1) * 8 + 0) * 32768;
                char* d = smem + (cur ? SM_BUF0 : SM_BUF1);
                gload16(s + stg, d + stg);
                gload16(s + stg + 16384, d + stg + 16384);
            }
            const char* B = smem + (cur ? SM_BUF1 : SM_BUF0);
            int cl = wc * 32 + wt * 16 + l15;                  // c-row in chunk
#pragma unroll
            for (int ks = 0; ks < 4; ++ks) {
                int byte = cl * 256 + ((ks * 64 + l4 * 16) ^ ((cl & 7) << 4));
                bfv8 qh = *(const bfv8*)(B + byte);
                of[j] = MFMA16(BC(uhf[ks]), qh, of[j]);
                of[j] = MFMA16(BC(ulf[ks]), qh, of[j]);
            }
            __syncthreads();
            cur ^= 1;
        }
    }

    // ---------- write split partials ----------
#pragma unroll
    for (int j = 0; j < 8; ++j)
#pragma unroll
        for (int q = 0; q < 4; ++q) {
            int gm = rb + wr * 16 + l4 * 4 + q;
            int cg = j * 64 + wc * 32 + wt * 16 + l15;
            pO[((size_t)gm * SPLITS + split) * C_DIM + cg] = of[j][q];
        }
    if (wt == 0 && wc == 0 && l15 == 0) {
#pragma unroll
        for (int q = 0; q < 4; ++q) {
            int gm = rb + wr * 16 + l4 * 4 + q;
            pM[gm * SPLITS + split] = Mr[q];
            pL[gm * SPLITS + split] = Lr[q];
        }
    }
}

// ======================= split-K combine =======================
__global__ void k_combine(const float* __restrict__ pO, const float* __restrict__ pM,
                          const float* __restrict__ pL, const float4* __restrict__ rowp,
                          float* __restrict__ out) {
    int r = blockIdx.x;
    int tid = threadIdx.x;   // 128 threads, 4 c's each
    float ce = rowp[r].z;
    float Ms[SPLITS], Ls[SPLITS];
    float M = -1e30f;
#pragma unroll
    for (int s = 0; s < SPLITS; ++s) {
        Ms[s] = pM[r * SPLITS + s];
        Ls[s] = pL[r * SPLITS + s];
        M = fmaxf(M, Ms[s]);
    }
    float es[SPLITS], L = 0.f;
#pragma unroll
    for (int s = 0; s < SPLITS; ++s) { es[s] = exp2f((Ms[s] - M) * ce); L += Ls[s] * es[s]; }
    float invL = 1.0f / L;
    f32x4 acc = (f32x4){0.f, 0.f, 0.f, 0.f};
#pragma unroll
    for (int s = 0; s < SPLITS; ++s) {
        f32x4 v = *(const f32x4*)(pO + ((size_t)r * SPLITS + s) * C_DIM + tid * 4);
        acc += v * es[s];
    }
    acc *= invL;
    *(f32x4*)(out + (size_t)r * C_DIM + tid * 4) = acc;
}

// ======================= launch =======================
extern "C" void kernel_launch(void* const* d_in, const int* in_sizes, int n_in,
                              void* d_out, int out_size, void* d_ws, size_t ws_size,
                              hipStream_t stream) {
    const float* x = (const float*)d_in[0];
    const int* t = (const int*)d_in[1];
    const float* A = (const float*)d_in[2];
    const float* bar_alpha = (const float*)d_in[3];
    float* out = (float*)d_out;
    char* ws = (char*)d_ws;
    if (ws_size < WS_NEED) return;

    char* imgA = ws + OFF_IMGA;
    char* imgC = ws + OFF_IMGC;
    unsigned short* Xh = (unsigned short*)(ws + OFF_XH);
    unsigned short* Xl = (unsigned short*)(ws + OFF_XL);
    float* Asq = (float*)(ws + OFF_ASQ);
    float4* rowp = (float4*)(ws + OFF_ROWP);
    float* pO = (float*)(ws + OFF_PO);
    float* pM = (float*)(ws + OFF_PM);
    float* pL = (float*)(ws + OFF_PL);

    (void)hipFuncSetAttribute((const void*)k_fused,
                              hipFuncAttributeMaxDynamicSharedMemorySize, SM_TOT);

    k_rows<<<R_DIM / 256, 256, 0, stream>>>(t, bar_alpha, rowp);
    k_splitx<<<(R_DIM * C_DIM / 8) / 256, 256, 0, stream>>>(x, (us8*)Xh, (us8*)Xl);
    k_imgA<<<GTILES * 8, 256, 0, stream>>>(A, imgA);
    k_imgC<<<GTILES * 8, 256, 0, stream>>>(A, imgC);
    k_asq<<<K_DIM / 4, 256, 0, stream>>>(A, Asq);
    k_fused<<<(R_DIM / BM) * SPLITS, 1024, SM_TOT, stream>>>(imgA, imgC, Xh, Xl,
                                                             Asq, rowp, pO, pM, pL);
    k_combine<<<R_DIM, 128, 0, stream>>>(pO, pM, pL, rowp, out);
}

// Round 10
// 536.656 us; speedup vs baseline: 1.8751x; 1.8751x over previous
//
#include <hip/hip_runtime.h>
#include <cstdint>
#include <cstddef>

// Problem constants (R,1,C) x, t, (K,C) A, (T,) bar_alpha
#define R_DIM 4096
#define K_DIM 16384
#define C_DIM 512
#define SPLITS 4                 // split over the 16384 k-dimension
#define BM 64                    // rows per workgroup
#define BK 128                   // k-tile
#define KRANGE (K_DIM / SPLITS)  // 4096
#define NTILES (KRANGE / BK)     // 32
#define GTILES (K_DIM / BK)      // 128 global tiles

typedef unsigned short us8 __attribute__((ext_vector_type(8)));
typedef float f32x4 __attribute__((ext_vector_type(4)));
typedef __bf16 bfv8 __attribute__((ext_vector_type(8)));

#define MFMA16(a, b, c) __builtin_amdgcn_mfma_f32_16x16x32_bf16((a), (b), (c), 0, 0, 0)
#define BC(v) __builtin_bit_cast(bfv8, (v))

__device__ __forceinline__ unsigned short f2bf(float v) {
    union { float f; unsigned u; } x; x.f = v;
    unsigned r = x.u + 0x7fffu + ((x.u >> 16) & 1u);  // RNE
    return (unsigned short)(r >> 16);
}
__device__ __forceinline__ float bf2f(unsigned short b) {
    union { unsigned u; float f; } x; x.u = ((unsigned)b) << 16;
    return x.f;
}

// async global->LDS, 16B per lane.
__device__ __forceinline__ void gload16(const char* g, char* l) {
    __builtin_amdgcn_global_load_lds(
        (const __attribute__((address_space(1))) void*)g,
        (__attribute__((address_space(3))) void*)l, 16, 0, 0);
}

// Counted-vmcnt phase barrier: N = vmem items issued in the CURRENT phase.
// The stage that must land was issued in the PREVIOUS phase, so everything
// issued this phase comes after it in the in-order vmcnt queue -> waiting to
// depth N guarantees it completed, without draining this phase's issues.
#define PHASE_BAR(N) do {                                                   \
    asm volatile("s_waitcnt vmcnt(" #N ") lgkmcnt(0)" ::: "memory");        \
    __builtin_amdgcn_s_barrier();                                           \
    __builtin_amdgcn_sched_barrier(0);                                      \
} while (0)

// ---------------- workspace layout (bytes) ----------------
#define OFF_IMGA ((size_t)0)          // [GTILES][8][32768]  32 MB   [128k][64c] images
#define OFF_IMGC ((size_t)33554432)   // [GTILES][8][32768]  32 MB   [64c][128k] images
#define OFF_XH   ((size_t)67108864)   // [R][C] bf16 hi    4 MB
#define OFF_XL   ((size_t)71303168)   // [R][C] bf16 lo    4 MB
#define OFF_ASQ  ((size_t)75497472)   // [K] f32          64 KB
#define OFF_ROWP ((size_t)75563008)   // [R] float4       64 KB  {sa, 0.5*sa*sa, inv*log2e, inv}
#define OFF_PO   ((size_t)75628544)   // [R][SPLITS][C] f32  32 MB
#define OFF_PM   ((size_t)109182976)  // [R][SPLITS] f32  64 KB
#define OFF_PL   ((size_t)109248512)  // [R][SPLITS] f32  64 KB
#define WS_NEED  ((size_t)109314048)

// ---------------- LDS layout (bytes) ----------------
#define SM_BUF0 0        // staging buffers: 3 x 32 KB (hi 16K, lo 16K each)
#define SM_BUF1 32768
#define SM_BUF2 65536
#define SM_U    98304    // u hi [64m][128k] bf16 swizzled  16 KB
#define SM_U2   114688   // u lo                            16 KB
#define SM_MX   131072   // float[2][64] tile-max exchange 512 B
#define SM_SM   131584   // float[2][64] tile-sum exchange 512 B
#define SM_TOT  132096

// ======================= prep kernels (identical to round 8) =======================

__global__ void k_rows(const int* __restrict__ t, const float* __restrict__ bar_alpha,
                       float4* __restrict__ rowp) {
    int r = blockIdx.x * 256 + threadIdx.x;
    if (r >= R_DIM) return;
    float ba = bar_alpha[t[r]];
    float sa = sqrtf(ba);
    float inv = 1.0f / (1.0f - ba);
    rowp[r] = make_float4(sa, 0.5f * sa * sa, inv * 1.4426950408889634f, inv);
}

__global__ void k_splitx(const float* __restrict__ x, us8* __restrict__ xh, us8* __restrict__ xl) {
    int i = blockIdx.x * 256 + threadIdx.x;   // group of 8 elements
    if (i >= R_DIM * C_DIM / 8) return;
    const float4* x4 = (const float4*)x + (size_t)i * 2;
    float v[8];
    float4 a = x4[0], b = x4[1];
    v[0]=a.x; v[1]=a.y; v[2]=a.z; v[3]=a.w; v[4]=b.x; v[5]=b.y; v[6]=b.z; v[7]=b.w;
    us8 h, l;
#pragma unroll
    for (int j = 0; j < 8; ++j) {
        unsigned short hb = f2bf(v[j]);
        h[j] = hb;
        l[j] = f2bf(v[j] - bf2f(hb));
    }
    xh[i] = h; xl[i] = l;
}

// Phase-A chunk images: block = (gt, j). pos = kl*128 + ((cb*16) ^ ((kl&7)<<4))
__global__ __launch_bounds__(256) void k_imgA(const float* __restrict__ A, char* __restrict__ img) {
    int gt = blockIdx.x >> 3, j = blockIdx.x & 7;
    char* base = img + (size_t)blockIdx.x * 32768;
    int t = threadIdx.x;
#pragma unroll
    for (int it = 0; it < 4; ++it) {
        int p = t + it * 256;
        int kl = p >> 3, cb = p & 7;
        const float* src = A + (size_t)(gt * 128 + kl) * C_DIM + j * 64 + cb * 8;
        us8 h, l;
#pragma unroll
        for (int q = 0; q < 8; ++q) {
            float v = src[q];
            unsigned short hb = f2bf(v);
            h[q] = hb; l[q] = f2bf(v - bf2f(hb));
        }
        int pos = kl * 128 + ((cb * 16) ^ ((kl & 7) << 4));
        *(us8*)(base + pos) = h;
        *(us8*)(base + 16384 + pos) = l;
    }
}

// Phase-C chunk images (transposed): pos = cl*256 + ((kb*16) ^ ((cl&7)<<4))
__global__ __launch_bounds__(256) void k_imgC(const float* __restrict__ A, char* __restrict__ img) {
    int gt = blockIdx.x >> 3, j = blockIdx.x & 7;
    char* base = img + (size_t)blockIdx.x * 32768;
    int t = threadIdx.x;
#pragma unroll
    for (int it = 0; it < 4; ++it) {
        int p = t + it * 256;
        int cl = p & 63, kb = p >> 6;
        us8 h, l;
#pragma unroll
        for (int q = 0; q < 8; ++q) {
            float v = A[(size_t)(gt * 128 + kb * 8 + q) * C_DIM + j * 64 + cl];
            unsigned short hb = f2bf(v);
            h[q] = hb; l[q] = f2bf(v - bf2f(hb));
        }
        int pos = cl * 256 + ((kb * 16) ^ ((cl & 7) << 4));
        *(us8*)(base + pos) = h;
        *(us8*)(base + 16384 + pos) = l;
    }
}

__global__ void k_asq(const float* __restrict__ A, float* __restrict__ Asq) {
    int wid = threadIdx.x >> 6, lane = threadIdx.x & 63;
    int k = blockIdx.x * 4 + wid;
    const float4* a4 = (const float4*)(A + (size_t)k * C_DIM);
    float s = 0.f;
#pragma unroll
    for (int j = 0; j < 2; ++j) {
        float4 v = a4[lane * 2 + j];
        s += v.x * v.x + v.y * v.y + v.z * v.z + v.w * v.w;
    }
#pragma unroll
    for (int off = 32; off; off >>= 1) s += __shfl_xor(s, off);
    if (lane == 0) Asq[k] = s;
}

// ======================= fused flash-style kernel =======================
// Round-8 engine FROZEN (512 thr, split=b&3, rb=b>>2, same math/images).
// ONE structural change: triple-buffered staging with counted-vmcnt barriers.
// Stage issued 2 phases ahead; barriers never drain vmcnt to 0 in the loop.
// Stage schedule: A_j stages chunk j+2 (A6->C0, A7->C1); B's __syncthreads
// drains C0/C1 under the softmax; C_j stages j+2 (C6/C7 -> next tile A0/A1,
// WRAPPED on the last tile so issue counts stay uniform).
__global__ __launch_bounds__(512, 2) void k_fused(
    const char* __restrict__ imgA, const char* __restrict__ imgC,
    const unsigned short* __restrict__ xh, const unsigned short* __restrict__ xl,
    const float* __restrict__ Asq, const float4* __restrict__ rowp,
    float* __restrict__ pO, float* __restrict__ pM, float* __restrict__ pL)
{
    extern __shared__ char smem[];
    const int tid = threadIdx.x;
    const int lane = tid & 63, wid = tid >> 6;
    const int wr = wid >> 1, wc = wid & 1;
    const int l15 = lane & 15, l4 = lane >> 4;
    const int rb = (blockIdx.x >> 2) * BM;
    const int split = blockIdx.x & (SPLITS - 1);

    float sa[4], hb[4], ce[4];
#pragma unroll
    for (int q = 0; q < 4; ++q) {
        float4 p = rowp[rb + wr * 16 + l4 * 4 + q];
        sa[q] = p.x; hb[q] = p.y; ce[q] = p.z;
    }
    float Mr[4], Lr[4];
#pragma unroll
    for (int q = 0; q < 4; ++q) { Mr[q] = -1e30f; Lr[q] = 0.f; }
    f32x4 of[8][2];   // [c-chunk j][c-frag f]
#pragma unroll
    for (int a = 0; a < 8; ++a)
#pragma unroll
        for (int b = 0; b < 2; ++b) of[a][b] = (f32x4){0.f, 0.f, 0.f, 0.f};

    const int xrow = (rb + wr * 16 + l15) * C_DIM;
    const int stg = tid * 16;

    // prologue: stage A(tile0,chunk0)->BUF0 and A(tile0,chunk1)->BUF1, drain.
    {
        const char* s0 = imgA + (size_t)(split * NTILES) * 8 * 32768;
        const char* s1 = s0 + 32768;
#pragma unroll
        for (int i = 0; i < 4; ++i) gload16(s0 + stg + i * 8192, smem + SM_BUF0 + stg + i * 8192);
#pragma unroll
        for (int i = 0; i < 4; ++i) gload16(s1 + stg + i * 8192, smem + SM_BUF1 + stg + i * 8192);
    }
    __syncthreads();
    int cur = 0;   // buffer index read by the current phase

    for (int kt = 0; kt < NTILES; ++kt) {
        const int gt = split * NTILES + kt;
        const int gtn = (kt == NTILES - 1) ? split * NTILES : gt + 1;  // wrapped next tile
        const int kbase = gt * BK;
        f32x4 sf[4];
#pragma unroll
        for (int f = 0; f < 4; ++f) sf[f] = (f32x4){0.f, 0.f, 0.f, 0.f};

        // ---------- Phase A: S[64m][128k] = (xh+xl)(Ah+Al)^T, 8 chunks of 64 c ----------
        us8 xbh[2][2], xbl[2][2];
#pragma unroll
        for (int j = 0; j < 8; ++j) {
            // x loads first (so their compiler-wait doesn't force stage drain)
            if (j == 0) {
#pragma unroll
                for (int cs = 0; cs < 2; ++cs) {
                    int off = xrow + 0 * 64 + cs * 32 + l4 * 8;
                    xbh[0][cs] = *(const us8*)(xh + off);
                    xbl[0][cs] = *(const us8*)(xl + off);
                }
            }
            if (j < 7) {
#pragma unroll
                for (int cs = 0; cs < 2; ++cs) {
                    int off = xrow + (j + 1) * 64 + cs * 32 + l4 * 8;
                    xbh[(j + 1) & 1][cs] = *(const us8*)(xh + off);
                    xbl[(j + 1) & 1][cs] = *(const us8*)(xl + off);
                }
            }
            // stage 2 phases ahead into buf[(cur+2)%3]
            {
                char* d = smem + ((cur + 2) % 3) * 32768 + stg;
                if (j < 6) {            // A chunk j+2 (hi+lo, 32 KB)
                    const char* s = imgA + ((size_t)gt * 8 + j + 2) * 32768;
#pragma unroll
                    for (int i = 0; i < 4; ++i) gload16(s + stg + i * 8192, d + i * 8192);
                } else if (j == 6) {    // C chunk 0 (hi-only, 16 KB)
                    const char* s = imgC + ((size_t)gt * 8 + 0) * 32768;
#pragma unroll
                    for (int i = 0; i < 2; ++i) gload16(s + stg + i * 8192, d + i * 8192);
                } else {                // j==7: C chunk 1 (hi-only)
                    const char* s = imgC + ((size_t)gt * 8 + 1) * 32768;
#pragma unroll
                    for (int i = 0; i < 2; ++i) gload16(s + stg + i * 8192, d + i * 8192);
                }
            }
            // MFMA on current buffer
            const char* B = smem + cur * 32768;
#pragma unroll
            for (int cs = 0; cs < 2; ++cs) {
#pragma unroll
                for (int f = 0; f < 4; ++f) {
                    int row = wc * 64 + f * 16 + l15;              // k-index in tile
                    int byte = row * 128 + ((cs * 64 + l4 * 16) ^ ((row & 7) << 4));
                    bfv8 qh = *(const bfv8*)(B + byte);
                    bfv8 ql = *(const bfv8*)(B + 16384 + byte);
                    sf[f] = MFMA16(BC(xbh[j & 1][cs]), qh, sf[f]);
                    sf[f] = MFMA16(BC(xbh[j & 1][cs]), ql, sf[f]);
                    sf[f] = MFMA16(BC(xbl[j & 1][cs]), qh, sf[f]);
                }
            }
            // counted barrier: N = vmem items issued THIS phase
            if (j == 0)      PHASE_BAR(8);   // xcold2 + xpref2 + stage4
            else if (j < 6)  PHASE_BAR(6);   // xpref2 + stage4
            else if (j == 6) PHASE_BAR(4);   // xpref2 + stage2
            else             PHASE_BAR(2);   // stage2
            cur = (cur + 1) % 3;
        }

        // ---------- Phase B: online softmax (r8 body; __syncthreads drains C0/C1) ----------
        float g[4][4];
#pragma unroll
        for (int f = 0; f < 4; ++f) {
            float asq = Asq[kbase + wc * 64 + f * 16 + l15];
#pragma unroll
            for (int q = 0; q < 4; ++q) g[f][q] = sa[q] * sf[f][q] - hb[q] * asq;
        }
        float tmax[4];
#pragma unroll
        for (int q = 0; q < 4; ++q)
            tmax[q] = fmaxf(fmaxf(g[0][q], g[1][q]), fmaxf(g[2][q], g[3][q]));
#pragma unroll
        for (int off = 1; off < 16; off <<= 1)
#pragma unroll
            for (int q = 0; q < 4; ++q) tmax[q] = fmaxf(tmax[q], __shfl_xor(tmax[q], off));
        float* smax = (float*)(smem + SM_MX);
        if (l15 == 0) {
#pragma unroll
            for (int q = 0; q < 4; ++q) smax[wc * 64 + wr * 16 + l4 * 4 + q] = tmax[q];
        }
        __syncthreads();
        float Mn[4], al[4];
#pragma unroll
        for (int q = 0; q < 4; ++q) {
            float other = smax[(wc ^ 1) * 64 + wr * 16 + l4 * 4 + q];
            float tm = fmaxf(tmax[q], other);
            Mn[q] = fmaxf(Mr[q], tm);
            al[q] = exp2f((Mr[q] - Mn[q]) * ce[q]);
        }
        float u[4][4], tsum[4] = {0.f, 0.f, 0.f, 0.f};
#pragma unroll
        for (int f = 0; f < 4; ++f)
#pragma unroll
            for (int q = 0; q < 4; ++q) {
                u[f][q] = exp2f((g[f][q] - Mn[q]) * ce[q]);
                tsum[q] += u[f][q];
            }
#pragma unroll
        for (int off = 1; off < 16; off <<= 1)
#pragma unroll
            for (int q = 0; q < 4; ++q) tsum[q] += __shfl_xor(tsum[q], off);
        float* ssum = (float*)(smem + SM_SM);
        if (l15 == 0) {
#pragma unroll
            for (int q = 0; q < 4; ++q) ssum[wc * 64 + wr * 16 + l4 * 4 + q] = tsum[q];
        }
        // write u (bf16 hi/lo) to LDS for GEMM2 A-operand
#pragma unroll
        for (int f = 0; f < 4; ++f)
#pragma unroll
            for (int q = 0; q < 4; ++q) {
                int m_loc = wr * 16 + l4 * 4 + q;
                int k_loc = wc * 64 + f * 16 + l15;
                int byte = (m_loc * 256 + k_loc * 2) ^ ((m_loc & 7) << 4);
                unsigned short uh = f2bf(u[f][q]);
                *(unsigned short*)(smem + SM_U + byte) = uh;
                *(unsigned short*)(smem + SM_U2 + byte) = f2bf(u[f][q] - bf2f(uh));
            }
        __syncthreads();
#pragma unroll
        for (int q = 0; q < 4; ++q) {
            float others = ssum[(wc ^ 1) * 64 + wr * 16 + l4 * 4 + q];
            Lr[q] = Lr[q] * al[q] + tsum[q] + others;
            Mr[q] = Mn[q];
        }
#pragma unroll
        for (int a = 0; a < 8; ++a)
#pragma unroll
            for (int b = 0; b < 2; ++b)
#pragma unroll
                for (int q = 0; q < 4; ++q) of[a][b][q] *= al[q];

        // ---------- Phase C: O[64m][512c] += (uh+ul) * Ah_tile, 8 chunks of 64 c ----------
        us8 uhf[4], ulf[4];
#pragma unroll
        for (int ks = 0; ks < 4; ++ks) {
            int m_loc = wr * 16 + l15;
            int byte = (m_loc * 256 + ks * 64 + l4 * 16) ^ ((m_loc & 7) << 4);
            uhf[ks] = *(const us8*)(smem + SM_U + byte);
            ulf[ks] = *(const us8*)(smem + SM_U2 + byte);
        }
#pragma unroll
        for (int j = 0; j < 8; ++j) {
            // stage 2 phases ahead
            {
                char* d = smem + ((cur + 2) % 3) * 32768 + stg;
                if (j < 6) {            // C chunk j+2 (hi-only)
                    const char* s = imgC + ((size_t)gt * 8 + j + 2) * 32768;
#pragma unroll
                    for (int i = 0; i < 2; ++i) gload16(s + stg + i * 8192, d + i * 8192);
                } else {                // j==6/7: next tile A chunk 0/1 (wrapped last tile)
                    const char* s = imgA + ((size_t)gtn * 8 + (j - 6)) * 32768;
#pragma unroll
                    for (int i = 0; i < 4; ++i) gload16(s + stg + i * 8192, d + i * 8192);
                }
            }
            const char* B = smem + cur * 32768;
#pragma unroll
            for (int f = 0; f < 2; ++f) {
                int cl = wc * 32 + f * 16 + l15;                   // c-row in chunk
#pragma unroll
                for (int ks = 0; ks < 4; ++ks) {
                    int byte = cl * 256 + ((ks * 64 + l4 * 16) ^ ((cl & 7) << 4));
                    bfv8 qh = *(const bfv8*)(B + byte);
                    of[j][f] = MFMA16(BC(uhf[ks]), qh, of[j][f]);
                    of[j][f] = MFMA16(BC(ulf[ks]), qh, of[j][f]);
                }
            }
            if (j < 6) PHASE_BAR(2);     // stage2
            else       PHASE_BAR(4);     // stage4
            cur = (cur + 1) % 3;
        }
    }

    // ---------- write split partials ----------
#pragma unroll
    for (int j = 0; j < 8; ++j)
#pragma unroll
        for (int f = 0; f < 2; ++f)
#pragma unroll
            for (int q = 0; q < 4; ++q) {
                int gm = rb + wr * 16 + l4 * 4 + q;
                int cg = j * 64 + wc * 32 + f * 16 + l15;
                pO[((size_t)gm * SPLITS + split) * C_DIM + cg] = of[j][f][q];
            }
    if (wc == 0 && l15 == 0) {
#pragma unroll
        for (int q = 0; q < 4; ++q) {
            int gm = rb + wr * 16 + l4 * 4 + q;
            pM[gm * SPLITS + split] = Mr[q];
            pL[gm * SPLITS + split] = Lr[q];
        }
    }
}

// ======================= split-K combine =======================
__global__ void k_combine(const float* __restrict__ pO, const float* __restrict__ pM,
                          const float* __restrict__ pL, const float4* __restrict__ rowp,
                          float* __restrict__ out) {
    int r = blockIdx.x;
    int tid = threadIdx.x;   // 128 threads, 4 c's each
    float ce = rowp[r].z;
    float Ms[SPLITS], Ls[SPLITS];
    float M = -1e30f;
#pragma unroll
    for (int s = 0; s < SPLITS; ++s) {
        Ms[s] = pM[r * SPLITS + s];
        Ls[s] = pL[r * SPLITS + s];
        M = fmaxf(M, Ms[s]);
    }
    float es[SPLITS], L = 0.f;
#pragma unroll
    for (int s = 0; s < SPLITS; ++s) { es[s] = exp2f((Ms[s] - M) * ce); L += Ls[s] * es[s]; }
    float invL = 1.0f / L;
    f32x4 acc = (f32x4){0.f, 0.f, 0.f, 0.f};
#pragma unroll
    for (int s = 0; s < SPLITS; ++s) {
        f32x4 v = *(const f32x4*)(pO + ((size_t)r * SPLITS + s) * C_DIM + tid * 4);
        acc += v * es[s];
    }
    acc *= invL;
    *(f32x4*)(out + (size_t)r * C_DIM + tid * 4) = acc;
}

// ======================= launch =======================
extern "C" void kernel_launch(void* const* d_in, const int* in_sizes, int n_in,
                              void* d_out, int out_size, void* d_ws, size_t ws_size,
                              hipStream_t stream) {
    const float* x = (const float*)d_in[0];
    const int* t = (const int*)d_in[1];
    const float* A = (const float*)d_in[2];
    const float* bar_alpha = (const float*)d_in[3];
    float* out = (float*)d_out;
    char* ws = (char*)d_ws;
    if (ws_size < WS_NEED) return;

    char* imgA = ws + OFF_IMGA;
    char* imgC = ws + OFF_IMGC;
    unsigned short* Xh = (unsigned short*)(ws + OFF_XH);
    unsigned short* Xl = (unsigned short*)(ws + OFF_XL);
    float* Asq = (float*)(ws + OFF_ASQ);
    float4* rowp = (float4*)(ws + OFF_ROWP);
    float* pO = (float*)(ws + OFF_PO);
    float* pM = (float*)(ws + OFF_PM);
    float* pL = (float*)(ws + OFF_PL);

    (void)hipFuncSetAttribute((const void*)k_fused,
                              hipFuncAttributeMaxDynamicSharedMemorySize, SM_TOT);

    k_rows<<<R_DIM / 256, 256, 0, stream>>>(t, bar_alpha, rowp);
    k_splitx<<<(R_DIM * C_DIM / 8) / 256, 256, 0, stream>>>(x, (us8*)Xh, (us8*)Xl);
    k_imgA<<<GTILES * 8, 256, 0, stream>>>(A, imgA);
    k_imgC<<<GTILES * 8, 256, 0, stream>>>(A, imgC);
    k_asq<<<K_DIM / 4, 256, 0, stream>>>(A, Asq);
    k_fused<<<(R_DIM / BM) * SPLITS, 512, SM_TOT, stream>>>(imgA, imgC, Xh, Xl,
                                                            Asq, rowp, pO, pM, pL);
    k_combine<<<R_DIM, 128, 0, stream>>>(pO, pM, pL, rowp, out);
}